// Round 6
// baseline (893.885 us; speedup 1.0000x reference)
//
#include <hip/hip_runtime.h>
#include <stdint.h>
#include <stddef.h>

// ---------- types & helpers ----------
typedef __bf16 bf16x8 __attribute__((ext_vector_type(8)));
typedef float  f32x4  __attribute__((ext_vector_type(4)));
typedef float  f32x2  __attribute__((ext_vector_type(2)));

static __device__ __forceinline__ float bf2f(unsigned short u) {
    union { unsigned int i; float f; } v; v.i = ((unsigned int)u) << 16; return v.f;
}
static __device__ __forceinline__ unsigned short f2bf(float f) {
    union { float f; unsigned int i; } v; v.f = f;
    unsigned int r = v.i + 0x7FFFu + ((v.i >> 16) & 1u);
    return (unsigned short)(r >> 16);
}
// packed f32x2 -> bf16x2 (RNE, same as manual f2bf) in one VALU op
static __device__ __forceinline__ unsigned cvt_pk_bf16(float a, float b) {
    unsigned r;
    asm volatile("v_cvt_pk_bf16_f32 %0, %1, %2" : "=v"(r) : "v"(a), "v"(b));
    return r;
}
// fp8 e4m3 (OCP on gfx950) encode via HW cvt
static __device__ __forceinline__ unsigned char f2fp8(float f) {
    return (unsigned char)(__builtin_amdgcn_cvt_pk_fp8_f32(f, f, 0, false) & 0xFF);
}

#define N_NODES 100000
#define N_EDGES 3200000
#define MPAD    100096      // multiple of 128
#define NB      782         // buckets of 128 rows: ceil(100000/128)
#define NBLK    256         // blocks for hist/scatter passes
#define EB      (N_EDGES / NBLK)   // 12500 edges per block
#define COLMASK 0xFFFFF     // col in low 20 bits; row&127 in bits 20..26

// ---------- CSR build: two-level bucket sort (write-locality-friendly) ----------

__global__ __launch_bounds__(256) void bucket_hist(const int* __restrict__ er, int* __restrict__ blockCnt) {
    __shared__ int h[NB];
    for (int i = threadIdx.x; i < NB; i += 256) h[i] = 0;
    __syncthreads();
    int base = blockIdx.x * EB;
    for (int e = base + threadIdx.x; e < base + EB; e += 256)
        atomicAdd(&h[er[e] >> 7], 1);
    __syncthreads();
    for (int i = threadIdx.x; i < NB; i += 256) blockCnt[blockIdx.x * NB + i] = h[i];
}

__global__ __launch_bounds__(256) void bucket_scan_a(const int* __restrict__ blockCnt,
                                                     int* __restrict__ blockOff,
                                                     int* __restrict__ bucketTotal) {
    __shared__ int s[256];
    int b = blockIdx.x, t = threadIdx.x;
    int v = blockCnt[t * NB + b];
    s[t] = v; __syncthreads();
    for (int off = 1; off < 256; off <<= 1) {
        int u = (t >= off) ? s[t - off] : 0;
        __syncthreads();
        s[t] += u;
        __syncthreads();
    }
    blockOff[t * NB + b] = s[t] - v;
    if (t == 255) bucketTotal[b] = s[255];
}

__global__ __launch_bounds__(1024) void bucket_scan_b(const int* __restrict__ bucketTotal,
                                                      int* __restrict__ bucketStart,
                                                      int* __restrict__ rp, int E,
                                                      int2* __restrict__ cpad) {
    __shared__ int s[1024];
    int t = threadIdx.x;
    int v = (t < NB) ? bucketTotal[t] : 0;
    s[t] = v; __syncthreads();
    for (int off = 1; off < 1024; off <<= 1) {
        int u = (t >= off) ? s[t - off] : 0;
        __syncthreads();
        s[t] += u;
        __syncthreads();
    }
    if (t < NB) bucketStart[t] = s[t] - v;
    if (t == 0) {
        bucketStart[NB] = E; rp[N_NODES] = E;
        // zero the 16-entry pad past cpack[E] so masked SPMM tails gather safely
        for (int i = 0; i < 16; i++) cpad[i] = make_int2(0, 0);
    }
}

// LDS-staged scatter: reorder the block's edges by bucket in LDS, then copy out
// in bucket order so global writes are coalesced runs (avg 16 edges = 128 B)
// instead of 64 scattered lines per wave store. Reuses blkCnt as the local hist.
__global__ __launch_bounds__(1024) void bucket_scatter(const int* __restrict__ er, const int* __restrict__ ec,
                                                       const float* __restrict__ ev,
                                                       const int* __restrict__ blkCnt,
                                                       const int* __restrict__ blockOff,
                                                       const int* __restrict__ bucketStart,
                                                       int2* __restrict__ cpackT) {
    __shared__ int2 buf[EB];      // 100000 B (gfx950: 160 KiB LDS/CU)
    __shared__ int  s[1024];
    __shared__ int  scanB[NB];    // local exclusive start per bucket
    __shared__ int  cur[NB];      // cursor during reorder; end position after
    int t = threadIdx.x;
    int v = (t < NB) ? blkCnt[blockIdx.x * NB + t] : 0;
    s[t] = v; __syncthreads();
    for (int off = 1; off < 1024; off <<= 1) {
        int u = (t >= off) ? s[t - off] : 0;
        __syncthreads();
        s[t] += u;
        __syncthreads();
    }
    if (t < NB) { scanB[t] = s[t] - v; cur[t] = s[t] - v; }
    __syncthreads();
    int base = blockIdx.x * EB;
    for (int e = base + t; e < base + EB; e += 1024) {
        int r = er[e];
        int p = atomicAdd(&cur[r >> 7], 1);
        buf[p] = make_int2(((r & 127) << 20) | ec[e], __float_as_int(ev[e]));
    }
    __syncthreads();
    // copy out: flat index i -> bucket b = first b with cur[b] > i (cur = end positions now)
    for (int i = t; i < EB; i += 1024) {
        int lo = 0, hi = NB - 1;
        while (lo < hi) { int mid = (lo + hi) >> 1; if (cur[mid] <= i) lo = mid + 1; else hi = mid; }
        int gpos = bucketStart[lo] + blockOff[blockIdx.x * NB + lo] + (i - scanB[lo]);
        cpackT[gpos] = buf[i];
    }
}

__global__ __launch_bounds__(256) void bucket_sort(const int2* __restrict__ cpackT,
                                                   const int* __restrict__ bucketStart,
                                                   int2* __restrict__ cpack, int* __restrict__ rp) {
    __shared__ int cnt[128];
    __shared__ int cursor[128];
    int b = blockIdx.x, t = threadIdx.x;
    int s = bucketStart[b], e = bucketStart[b + 1];
    if (t < 128) cnt[t] = 0;
    __syncthreads();
    for (int j = s + t; j < e; j += 256)
        atomicAdd(&cnt[cpackT[j].x >> 20], 1);
    __syncthreads();
    int val = (t < 128) ? cnt[t] : 0;
    for (int off = 1; off < 128; off <<= 1) {
        int u = (t < 128 && t >= off) ? cnt[t - off] : 0;
        __syncthreads();
        if (t < 128) cnt[t] += u;
        __syncthreads();
    }
    if (t < 128) {
        int excl = cnt[t] - val;
        cursor[t] = s + excl;
        int gr = b * 128 + t;
        if (gr < N_NODES) rp[gr] = s + excl;
    }
    __syncthreads();
    for (int j = s + t; j < e; j += 256) {
        int2 v = cpackT[j];
        int p = atomicAdd(&cursor[v.x >> 20], 1);
        // store pre-shifted byte offset (col*256) so SPMM gather addr is one s_add
        cpack[p] = make_int2((v.x & COLMASK) << 8, v.y);
    }
}

// ---------- fused weight transpose + bf16 convert (all 3 weights, one launch) ----------
// W[K][Nc] -> Wt[Nc][K]
__global__ __launch_bounds__(256) void transpose_all(const float* __restrict__ W1, unsigned short* __restrict__ Wt1,
                                                     const float* __restrict__ W2, unsigned short* __restrict__ Wt2,
                                                     const float* __restrict__ W3, unsigned short* __restrict__ Wt3) {
    int i = blockIdx.x * 256 + threadIdx.x;
    const int S1 = 512 * 256, S2 = 256 * 256, S3 = 256 * 64;
    if (i < S1) {
        int k = i / 256, n = i % 256;
        Wt1[(size_t)n * 512 + k] = f2bf(W1[i]);
    } else if (i < S1 + S2) {
        int j = i - S1; int k = j / 256, n = j % 256;
        Wt2[(size_t)n * 256 + k] = f2bf(W2[j]);
    } else if (i < S1 + S2 + S3) {
        int j = i - S1 - S2; int k = j / 64, n = j % 64;
        Wt3[(size_t)n * 256 + k] = f2bf(W3[j]);
    }
}

// ---------- MFMA GEMM: C = A[Mpad][K] @ Bt[Nc][K]^T ; OUT: 0=bf16, 1=fp8 ----------
// R5 post-mortem: stage->barrier->compute->barrier has ~0 memory/compute overlap
// (gemm1: MfmaUtil 8.5%, HBM 24%, Occ 58% -- all idle; Little's law shows ~2.5KB
// outstanding/CU). Fix = 2-phase reg-prefetch (T3-minimal + T14): issue tile t+1
// global loads into REGISTERS before computing tile t from LDS; vmcnt drain only
// at the post-barrier LDS write. Costs ~24 VGPR, LDS unchanged.
template<int BM, int BN, int BK, int WROWS, int WCOLS, bool A_F32, int OUT>
__global__ __launch_bounds__(WROWS* WCOLS * 64) void gemm_mfma(const void* __restrict__ Aptr,
                                                 const unsigned short* __restrict__ Bt,
                                                 void* __restrict__ Cptr,
                                                 int K, int Nc, int Mclamp) {
    constexpr int THREADS = WROWS * WCOLS * 64;
    constexpr int WM = BM / WROWS, WN = BN / WCOLS;
    constexpr int MT = WM / 16, NT = WN / 16;
    constexpr int LDA = BK + 8;
    constexpr int KV = BK / 8;
    constexpr int A_ITERS = (BM * KV) / THREADS;
    constexpr int B_ITERS = (BN * KV) / THREADS;

    __shared__ unsigned short lds_a[BM * LDA];
    __shared__ unsigned short lds_b[BN * LDA];

    const int tid  = threadIdx.x;
    const int wid  = tid >> 6, lane = tid & 63;
    const int wrow = wid / WCOLS, wcol = wid % WCOLS;
    const int bm = blockIdx.x * BM, bn = blockIdx.y * BN;
    const int r = lane & 15, q = lane >> 4;

    const float*          Af = (const float*)Aptr;
    const unsigned short* Ab = (const unsigned short*)Aptr;

    f32x4 acc[MT][NT];
    f32x4 zero = {0.f, 0.f, 0.f, 0.f};
#pragma unroll
    for (int mi = 0; mi < MT; mi++)
#pragma unroll
        for (int ni = 0; ni < NT; ni++) acc[mi][ni] = zero;

    // register staging buffers (prefetch tile)
    float4 raf[A_ITERS][2];   // A_F32 path
    uint4  rab[A_ITERS];      // A bf16 path
    uint4  rb[B_ITERS];

    auto load_tile = [&](int k0) {
#pragma unroll
        for (int it = 0; it < A_ITERS; it++) {
            int v = tid + it * THREADS;
            int row = v / KV, kc = (v % KV) * 8;
            int grow = bm + row;
            if constexpr (A_F32) {
                grow = (grow <= Mclamp) ? grow : Mclamp;
                const float4* pp = (const float4*)(Af + (size_t)grow * K + k0 + kc);
                raf[it][0] = pp[0];
                raf[it][1] = pp[1];
            } else {
                rab[it] = *(const uint4*)(Ab + (size_t)grow * K + k0 + kc);
            }
        }
#pragma unroll
        for (int it = 0; it < B_ITERS; it++) {
            int v = tid + it * THREADS;
            int row = v / KV, kc = (v % KV) * 8;
            rb[it] = *(const uint4*)(Bt + (size_t)(bn + row) * K + k0 + kc);
        }
    };

    auto write_lds = [&]() {
#pragma unroll
        for (int it = 0; it < A_ITERS; it++) {
            int v = tid + it * THREADS;
            int row = v / KV, kc = (v % KV) * 8;
            uint4 d;
            if constexpr (A_F32) {
                d.x = cvt_pk_bf16(raf[it][0].x, raf[it][0].y);
                d.y = cvt_pk_bf16(raf[it][0].z, raf[it][0].w);
                d.z = cvt_pk_bf16(raf[it][1].x, raf[it][1].y);
                d.w = cvt_pk_bf16(raf[it][1].z, raf[it][1].w);
            } else {
                d = rab[it];
            }
            *(uint4*)&lds_a[row * LDA + kc] = d;
        }
#pragma unroll
        for (int it = 0; it < B_ITERS; it++) {
            int v = tid + it * THREADS;
            int row = v / KV, kc = (v % KV) * 8;
            *(uint4*)&lds_b[row * LDA + kc] = rb[it];
        }
    };

    auto compute = [&]() {
#pragma unroll
        for (int kk = 0; kk < BK; kk += 32) {
            bf16x8 av[MT], bv[NT];
#pragma unroll
            for (int mi = 0; mi < MT; mi++)
                av[mi] = *(const bf16x8*)&lds_a[(wrow * WM + mi * 16 + r) * LDA + kk + q * 8];
#pragma unroll
            for (int ni = 0; ni < NT; ni++)
                bv[ni] = *(const bf16x8*)&lds_b[(wcol * WN + ni * 16 + r) * LDA + kk + q * 8];
#pragma unroll
            for (int mi = 0; mi < MT; mi++)
#pragma unroll
                for (int ni = 0; ni < NT; ni++)
                    acc[mi][ni] = __builtin_amdgcn_mfma_f32_16x16x32_bf16(av[mi], bv[ni], acc[mi][ni], 0, 0, 0);
        }
    };

    // 2-phase pipeline: loads for tile t+1 fly while tile t computes
    load_tile(0);
    write_lds();
    __syncthreads();
    for (int k0 = BK; k0 < K; k0 += BK) {
        load_tile(k0);      // issue next-tile global loads (no wait)
        compute();          // ds_read + MFMA on current LDS tile
        __syncthreads();    // all waves done reading LDS
        write_lds();        // vmcnt drain here; ds_write next tile
        __syncthreads();
    }
    compute();              // last tile

    // epilogue: C/D layout col = lane&15, row = q*4 + d
#pragma unroll
    for (int mi = 0; mi < MT; mi++) {
        int row = bm + wrow * WM + mi * 16 + q * 4;
#pragma unroll
        for (int ni = 0; ni < NT; ni++) {
            int cc = bn + wcol * WN + ni * 16 + r;
#pragma unroll
            for (int d = 0; d < 4; d++) {
                if constexpr (OUT == 0) {
                    ((unsigned short*)Cptr)[(size_t)(row + d) * Nc + cc] = f2bf(acc[mi][ni][d]);
                } else {
                    ((unsigned char*)Cptr)[(size_t)(row + d) * Nc + cc] = f2fp8(acc[mi][ni][d]);
                }
            }
        }
    }
}

// ---------- SPMM (F=256, fp8 Z): wave per row, scalarized edge stream ----------
// R6: unroll 32 so one gather batch covers a whole average row (32 edges) ->
// 32 gathers + 8 edge-block loads in flight (vmcnt max 63 ok).
__global__ __launch_bounds__(256) void spmm_f256_fp8(const int* __restrict__ rp, const int2* __restrict__ cpack,
                                                     const unsigned char* __restrict__ Z8,
                                                     const float* __restrict__ bias, unsigned short* __restrict__ H, int N) {
    int w = __builtin_amdgcn_readfirstlane((int)((blockIdx.x * 256 + threadIdx.x) >> 6));
    if (w >= N) return;
    int lane = threadIdx.x & 63;
    int f4 = lane * 4;                       // byte offset into 256-B fp8 row
    int s = __builtin_amdgcn_readfirstlane(rp[w]);
    int e = __builtin_amdgcn_readfirstlane(rp[w + 1]);
    f32x2 acc01 = {0.f, 0.f}, acc23 = {0.f, 0.f};
    int j = s;

#define EDGE_BLK(UN, MASKED) { \
        int2 eb[UN]; \
        _Pragma("unroll") \
        for (int t = 0; t < UN; t++) eb[t] = cpack[j + t]; \
        _Pragma("unroll") \
        for (int t = 0; t < UN; t++) { \
            int ex = __builtin_amdgcn_readfirstlane(eb[t].x); \
            int ew = __builtin_amdgcn_readfirstlane(eb[t].y); \
            if (MASKED) ew = (j + t < e) ? ew : 0; \
            float wt = __int_as_float(ew); \
            unsigned z = *(const unsigned*)(Z8 + (size_t)(unsigned)ex + f4); \
            f32x2 lo = __builtin_amdgcn_cvt_pk_f32_fp8((int)z, false); \
            f32x2 hi = __builtin_amdgcn_cvt_pk_f32_fp8((int)z, true);  \
            f32x2 wv = {wt, wt}; \
            acc01 += wv * lo; \
            acc23 += wv * hi; \
        } }

    for (; j + 32 <= e; j += 32) EDGE_BLK(32, false)
    for (; j < e; j += 8)        EDGE_BLK(8,  true)   // masked tail; cpack padded by 16 zeros
#undef EDGE_BLK

    float4 b = *(const float4*)(bias + f4);
    float a0 = fmaxf(acc01.x + b.x, 0.f), a1 = fmaxf(acc01.y + b.y, 0.f);
    float a2 = fmaxf(acc23.x + b.z, 0.f), a3 = fmaxf(acc23.y + b.w, 0.f);
    ushort4 o; o.x = f2bf(a0); o.y = f2bf(a1); o.z = f2bf(a2); o.w = f2bf(a3);
    *(ushort4*)(H + (size_t)w * 256 + f4) = o;
}

// ---------- SPMM (F=64, bf16 Z) + bias + log_softmax ----------
__global__ __launch_bounds__(256) void spmm_f64_lsm(const int* __restrict__ rp, const int2* __restrict__ cpack,
                                                    const unsigned short* __restrict__ Z,
                                                    const float* __restrict__ bias, float* __restrict__ out, int N) {
    int w = __builtin_amdgcn_readfirstlane((int)((blockIdx.x * 256 + threadIdx.x) >> 6));
    if (w >= N) return;
    int lane = threadIdx.x & 63;
    const unsigned char* Zb = (const unsigned char*)Z;
    int s = __builtin_amdgcn_readfirstlane(rp[w]);
    int e = __builtin_amdgcn_readfirstlane(rp[w + 1]);
    float acc = 0.f;
    int j = s;

#define EDGE_BLK(UN, MASKED) { \
        int2 eb[UN]; \
        _Pragma("unroll") \
        for (int t = 0; t < UN; t++) eb[t] = cpack[j + t]; \
        _Pragma("unroll") \
        for (int t = 0; t < UN; t++) { \
            int ex = __builtin_amdgcn_readfirstlane(eb[t].x); \
            int ew = __builtin_amdgcn_readfirstlane(eb[t].y); \
            if (MASKED) ew = (j + t < e) ? ew : 0; \
            float wt = __int_as_float(ew); \
            /* ex = col*256 ; bf16 row stride = 128 B -> ex>>1 */ \
            unsigned short z = *(const unsigned short*)(Zb + (size_t)(unsigned)(ex >> 1) + lane * 2); \
            acc += wt * bf2f(z); \
        } }

    for (; j + 16 <= e; j += 16) EDGE_BLK(16, false)
    for (; j < e; j += 4)        EDGE_BLK(4, true)   // masked tail; cpack padded by 16 zeros
#undef EDGE_BLK

    float a = acc + bias[lane];
    float m = a;
#pragma unroll
    for (int off = 32; off >= 1; off >>= 1) m = fmaxf(m, __shfl_xor(m, off, 64));
    float p = __expf(a - m);
    float sum = p;
#pragma unroll
    for (int off = 32; off >= 1; off >>= 1) sum += __shfl_xor(sum, off, 64);
    out[(size_t)w * 64 + lane] = a - m - __logf(sum);
}

// ---------- launch ----------
extern "C" void kernel_launch(void* const* d_in, const int* in_sizes, int n_in,
                              void* d_out, int out_size, void* d_ws, size_t ws_size,
                              hipStream_t stream) {
    const float* x  = (const float*)d_in[0];
    const int*   er = (const int*)  d_in[1];
    const int*   ec = (const int*)  d_in[2];
    const float* ev = (const float*)d_in[3];
    const float* W1 = (const float*)d_in[4];
    const float* b1 = (const float*)d_in[5];
    const float* W2 = (const float*)d_in[6];
    const float* b2 = (const float*)d_in[7];
    const float* W3 = (const float*)d_in[8];
    const float* b3 = (const float*)d_in[9];

    const int N = N_NODES, E = N_EDGES;

    char* p = (char*)d_ws;
    auto alloc = [&](size_t bytes) -> char* {
        char* q = p; p += (bytes + 255) & ~(size_t)255; return q;
    };
    unsigned short* Wt1    = (unsigned short*)alloc((size_t)256 * 512 * 2);
    unsigned short* Wt2    = (unsigned short*)alloc((size_t)256 * 256 * 2);
    unsigned short* Wt3    = (unsigned short*)alloc((size_t)64  * 256 * 2);
    int*            rp     = (int*)  alloc((size_t)(N + 1) * 4);
    int*            blkCnt = (int*)  alloc((size_t)NBLK * NB * 4);
    int*            blkOff = (int*)  alloc((size_t)NBLK * NB * 4);
    int*            bktTot = (int*)  alloc((size_t)NB * 4);
    int*            bktSt  = (int*)  alloc((size_t)(NB + 1) * 4);
    int2*           cpack  = (int2*) alloc((size_t)(E + 16) * 8);   // +16 zero pad for masked tails
    unsigned char*  Z8     = (unsigned char*) alloc((size_t)MPAD * 256);      // fp8 Z (layers 1-2)
    unsigned short* bufA   = (unsigned short*)alloc((size_t)MPAD * 256 * 2);  // bf16 Z (layer 3) / cpackT overlay
    unsigned short* bufB   = (unsigned short*)alloc((size_t)MPAD * 256 * 2);  // bf16 H
    int2*           cpackT = (int2*)bufA;   // overlay: bufA unused until gemm3

    // CSR build
    bucket_hist   <<<NBLK, 256, 0, stream>>>(er, blkCnt);
    bucket_scan_a <<<NB,   256, 0, stream>>>(blkCnt, blkOff, bktTot);
    bucket_scan_b <<<1,   1024, 0, stream>>>(bktTot, bktSt, rp, E, cpack + E);
    bucket_scatter<<<NBLK, 1024, 0, stream>>>(er, ec, ev, blkCnt, blkOff, bktSt, cpackT);
    bucket_sort   <<<NB,   256, 0, stream>>>(cpackT, bktSt, cpack, rp);

    // weights -> bf16 transposed (one launch)
    transpose_all<<<(512*256 + 256*256 + 256*64 + 255) / 256, 256, 0, stream>>>(W1, Wt1, W2, Wt2, W3, Wt3);

    // layer 1: Z8 = fp8(x @ W1) ; H = relu(spmm(Z8) + b1)
    // 8 waves (4x2), per-wave 32x64 -> acc 32 AGPR; 2-phase reg-prefetch pipeline
    gemm_mfma<128, 128, 64, 4, 2, true , 1><<<dim3(MPAD / 128, 2), 512, 0, stream>>>(x,    Wt1, Z8,   512, 256, N - 1);
    spmm_f256_fp8<<<N / 4, 256, 0, stream>>>(rp, cpack, Z8, b1, bufB, N);
    // layer 2
    gemm_mfma<128, 128, 64, 4, 2, false, 1><<<dim3(MPAD / 128, 2), 512, 0, stream>>>(bufB, Wt2, Z8,   256, 256, N - 1);
    spmm_f256_fp8<<<N / 4, 256, 0, stream>>>(rp, cpack, Z8, b2, bufB, N);
    // layer 3 (bf16 Z to protect logits) + fused bias + log_softmax
    gemm_mfma<128, 64, 64, 4, 2, false, 0><<<dim3(MPAD / 128, 1), 512, 0, stream>>>(bufB, Wt3, bufA, 256, 64, N - 1);
    spmm_f64_lsm<<<N / 4, 256, 0, stream>>>(rp, cpack, bufA, b3, (float*)d_out, N);
}

// Round 7
// 775.636 us; speedup vs baseline: 1.1525x; 1.1525x over previous
//
#include <hip/hip_runtime.h>
#include <stdint.h>
#include <stddef.h>

// ---------- types & helpers ----------
typedef __bf16 bf16x8 __attribute__((ext_vector_type(8)));
typedef float  f32x4  __attribute__((ext_vector_type(4)));
typedef float  f32x2  __attribute__((ext_vector_type(2)));

static __device__ __forceinline__ float bf2f(unsigned short u) {
    union { unsigned int i; float f; } v; v.i = ((unsigned int)u) << 16; return v.f;
}
static __device__ __forceinline__ unsigned short f2bf(float f) {
    union { float f; unsigned int i; } v; v.f = f;
    unsigned int r = v.i + 0x7FFFu + ((v.i >> 16) & 1u);
    return (unsigned short)(r >> 16);
}
// packed f32x2 -> bf16x2 (RNE, same as manual f2bf) in one VALU op
static __device__ __forceinline__ unsigned cvt_pk_bf16(float a, float b) {
    unsigned r;
    asm volatile("v_cvt_pk_bf16_f32 %0, %1, %2" : "=v"(r) : "v"(a), "v"(b));
    return r;
}
// fp8 e4m3 (OCP on gfx950) encode via HW cvt
static __device__ __forceinline__ unsigned char f2fp8(float f) {
    return (unsigned char)(__builtin_amdgcn_cvt_pk_fp8_f32(f, f, 0, false) & 0xFF);
}
// async global->LDS, 16 B per lane (dest: wave-uniform base + lane*16)
static __device__ __forceinline__ void gload_lds16(const void* g, void* l) {
    __builtin_amdgcn_global_load_lds(
        (const __attribute__((address_space(1))) unsigned int*)g,
        (__attribute__((address_space(3))) unsigned int*)l, 16, 0, 0);
}

#define N_NODES 100000
#define N_EDGES 3200000
#define MPAD    100096      // multiple of 128
#define NB      782         // buckets of 128 rows: ceil(100000/128)
#define NBLK    256         // blocks for hist/scatter passes
#define EB      (N_EDGES / NBLK)   // 12500 edges per block
#define COLMASK 0xFFFFF     // col in low 20 bits; row&127 in bits 20..26

// ---------- CSR build: two-level bucket sort (write-locality-friendly) ----------

__global__ __launch_bounds__(256) void bucket_hist(const int* __restrict__ er, int* __restrict__ blockCnt) {
    __shared__ int h[NB];
    for (int i = threadIdx.x; i < NB; i += 256) h[i] = 0;
    __syncthreads();
    int base = blockIdx.x * EB;
    for (int e = base + threadIdx.x; e < base + EB; e += 256)
        atomicAdd(&h[er[e] >> 7], 1);
    __syncthreads();
    for (int i = threadIdx.x; i < NB; i += 256) blockCnt[blockIdx.x * NB + i] = h[i];
}

__global__ __launch_bounds__(256) void bucket_scan_a(const int* __restrict__ blockCnt,
                                                     int* __restrict__ blockOff,
                                                     int* __restrict__ bucketTotal) {
    __shared__ int s[256];
    int b = blockIdx.x, t = threadIdx.x;
    int v = blockCnt[t * NB + b];
    s[t] = v; __syncthreads();
    for (int off = 1; off < 256; off <<= 1) {
        int u = (t >= off) ? s[t - off] : 0;
        __syncthreads();
        s[t] += u;
        __syncthreads();
    }
    blockOff[t * NB + b] = s[t] - v;
    if (t == 255) bucketTotal[b] = s[255];
}

__global__ __launch_bounds__(1024) void bucket_scan_b(const int* __restrict__ bucketTotal,
                                                      int* __restrict__ bucketStart,
                                                      int* __restrict__ rp, int E,
                                                      int2* __restrict__ cpad) {
    __shared__ int s[1024];
    int t = threadIdx.x;
    int v = (t < NB) ? bucketTotal[t] : 0;
    s[t] = v; __syncthreads();
    for (int off = 1; off < 1024; off <<= 1) {
        int u = (t >= off) ? s[t - off] : 0;
        __syncthreads();
        s[t] += u;
        __syncthreads();
    }
    if (t < NB) bucketStart[t] = s[t] - v;
    if (t == 0) {
        bucketStart[NB] = E; rp[N_NODES] = E;
        // zero the 16-entry pad past cpack[E] so masked SPMM tails gather safely
        for (int i = 0; i < 16; i++) cpad[i] = make_int2(0, 0);
    }
}

// LDS-staged scatter: reorder the block's edges by bucket in LDS, then copy out
// in bucket order so global writes are coalesced runs (avg 16 edges = 128 B).
__global__ __launch_bounds__(1024) void bucket_scatter(const int* __restrict__ er, const int* __restrict__ ec,
                                                       const float* __restrict__ ev,
                                                       const int* __restrict__ blkCnt,
                                                       const int* __restrict__ blockOff,
                                                       const int* __restrict__ bucketStart,
                                                       int2* __restrict__ cpackT) {
    __shared__ int2 buf[EB];      // 100000 B (gfx950: 160 KiB LDS/CU)
    __shared__ int  s[1024];
    __shared__ int  scanB[NB];    // local exclusive start per bucket
    __shared__ int  cur[NB];      // cursor during reorder; end position after
    int t = threadIdx.x;
    int v = (t < NB) ? blkCnt[blockIdx.x * NB + t] : 0;
    s[t] = v; __syncthreads();
    for (int off = 1; off < 1024; off <<= 1) {
        int u = (t >= off) ? s[t - off] : 0;
        __syncthreads();
        s[t] += u;
        __syncthreads();
    }
    if (t < NB) { scanB[t] = s[t] - v; cur[t] = s[t] - v; }
    __syncthreads();
    int base = blockIdx.x * EB;
    for (int e = base + t; e < base + EB; e += 1024) {
        int r = er[e];
        int p = atomicAdd(&cur[r >> 7], 1);
        buf[p] = make_int2(((r & 127) << 20) | ec[e], __float_as_int(ev[e]));
    }
    __syncthreads();
    // copy out: flat index i -> bucket b = first b with cur[b] > i (cur = end positions now)
    for (int i = t; i < EB; i += 1024) {
        int lo = 0, hi = NB - 1;
        while (lo < hi) { int mid = (lo + hi) >> 1; if (cur[mid] <= i) lo = mid + 1; else hi = mid; }
        int gpos = bucketStart[lo] + blockOff[blockIdx.x * NB + lo] + (i - scanB[lo]);
        cpackT[gpos] = buf[i];
    }
}

__global__ __launch_bounds__(256) void bucket_sort(const int2* __restrict__ cpackT,
                                                   const int* __restrict__ bucketStart,
                                                   int2* __restrict__ cpack, int* __restrict__ rp) {
    __shared__ int cnt[128];
    __shared__ int cursor[128];
    int b = blockIdx.x, t = threadIdx.x;
    int s = bucketStart[b], e = bucketStart[b + 1];
    if (t < 128) cnt[t] = 0;
    __syncthreads();
    for (int j = s + t; j < e; j += 256)
        atomicAdd(&cnt[cpackT[j].x >> 20], 1);
    __syncthreads();
    int val = (t < 128) ? cnt[t] : 0;
    for (int off = 1; off < 128; off <<= 1) {
        int u = (t < 128 && t >= off) ? cnt[t - off] : 0;
        __syncthreads();
        if (t < 128) cnt[t] += u;
        __syncthreads();
    }
    if (t < 128) {
        int excl = cnt[t] - val;
        cursor[t] = s + excl;
        int gr = b * 128 + t;
        if (gr < N_NODES) rp[gr] = s + excl;
    }
    __syncthreads();
    for (int j = s + t; j < e; j += 256) {
        int2 v = cpackT[j];
        int p = atomicAdd(&cursor[v.x >> 20], 1);
        // store pre-shifted byte offset (col*256) so SPMM gather addr is one s_add
        cpack[p] = make_int2((v.x & COLMASK) << 8, v.y);
    }
}

// ---------- fused weight transpose + bf16 convert (all 3 weights, one launch) ----------
// W[K][Nc] -> Wt[Nc][K]
__global__ __launch_bounds__(256) void transpose_all(const float* __restrict__ W1, unsigned short* __restrict__ Wt1,
                                                     const float* __restrict__ W2, unsigned short* __restrict__ Wt2,
                                                     const float* __restrict__ W3, unsigned short* __restrict__ Wt3) {
    int i = blockIdx.x * 256 + threadIdx.x;
    const int S1 = 512 * 256, S2 = 256 * 256, S3 = 256 * 64;
    if (i < S1) {
        int k = i / 256, n = i % 256;
        Wt1[(size_t)n * 512 + k] = f2bf(W1[i]);
    } else if (i < S1 + S2) {
        int j = i - S1; int k = j / 256, n = j % 256;
        Wt2[(size_t)n * 256 + k] = f2bf(W2[j]);
    } else if (i < S1 + S2 + S3) {
        int j = i - S1 - S2; int k = j / 64, n = j % 64;
        Wt3[(size_t)n * 256 + k] = f2bf(W3[j]);
    }
}

// ---------- MFMA GEMM: C = A[Mpad][K] @ Bt[Nc][K]^T ; OUT: 0=bf16, 1=fp8 ----------
// R7: staging via __builtin_amdgcn_global_load_lds (16 B/lane, m97 ladder +67%).
// LDS is LINEAR (no pad, gload_lds requires it); bank conflicts handled by the
// HK source-swizzle pattern (m173): stage chunk q from global chunk q^(row&7),
// read with the matching XOR. 16-B chunks; KV = BK/8 = 8 chunks/row.
// gemm1's f32 A path keeps reg-staging (needs cvt) but ds_writes to swizzled
// offsets; its B panel is still async.
template<int BM, int BN, int BK, int WROWS, int WCOLS, bool A_F32, int OUT>
__global__ __launch_bounds__(WROWS* WCOLS * 64) void gemm_mfma(const void* __restrict__ Aptr,
                                                 const unsigned short* __restrict__ Bt,
                                                 void* __restrict__ Cptr,
                                                 int K, int Nc, int Mclamp) {
    constexpr int THREADS = WROWS * WCOLS * 64;
    constexpr int WM = BM / WROWS, WN = BN / WCOLS;
    constexpr int MT = WM / 16, NT = WN / 16;
    constexpr int KV = BK / 8;               // 16-B chunks per row (BK=64 -> 8)
    constexpr int A_ITERS = (BM * KV) / THREADS;
    constexpr int B_ITERS = (BN * KV) / THREADS;

    __shared__ unsigned short lds_a[BM * BK];
    __shared__ unsigned short lds_b[BN * BK];

    const int tid  = threadIdx.x;
    const int wid  = tid >> 6, lane = tid & 63;
    const int wrow = wid / WCOLS, wcol = wid % WCOLS;
    const int bm = blockIdx.x * BM, bn = blockIdx.y * BN;
    const int r = lane & 15, q = lane >> 4;

    const float*          Af = (const float*)Aptr;
    const unsigned short* Ab = (const unsigned short*)Aptr;

    f32x4 acc[MT][NT];
    f32x4 zero = {0.f, 0.f, 0.f, 0.f};
#pragma unroll
    for (int mi = 0; mi < MT; mi++)
#pragma unroll
        for (int ni = 0; ni < NT; ni++) acc[mi][ni] = zero;

    for (int k0 = 0; k0 < K; k0 += BK) {
        // ---- B panel: async, inverse-swizzled source ----
#pragma unroll
        for (int it = 0; it < B_ITERS; it++) {
            int v = tid + it * THREADS;
            int row = v / KV, qc = v % KV;
            int qs = qc ^ (row & 7);
            gload_lds16(Bt + (size_t)(bn + row) * K + k0 + qs * 8, &lds_b[v * 8]);
        }
        // ---- A panel ----
#pragma unroll
        for (int it = 0; it < A_ITERS; it++) {
            int v = tid + it * THREADS;
            int row = v / KV, qc = v % KV;
            if constexpr (A_F32) {
                // load global f32 chunk (row,qc), cvt, write LDS at (row, qc^(row&7))
                int grow = bm + row;
                grow = (grow <= Mclamp) ? grow : Mclamp;
                const float4* pp = (const float4*)(Af + (size_t)grow * K + k0 + qc * 8);
                float4 f0 = pp[0], f1 = pp[1];
                uint4 d;
                d.x = cvt_pk_bf16(f0.x, f0.y);
                d.y = cvt_pk_bf16(f0.z, f0.w);
                d.z = cvt_pk_bf16(f1.x, f1.y);
                d.w = cvt_pk_bf16(f1.z, f1.w);
                *(uint4*)&lds_a[row * BK + (qc ^ (row & 7)) * 8] = d;
            } else {
                int qs = qc ^ (row & 7);
                gload_lds16(Ab + (size_t)(bm + row) * K + k0 + qs * 8, &lds_a[v * 8]);
            }
        }
        __syncthreads();   // drains vmcnt (gload_lds) + lgkm (ds_write)

#pragma unroll
        for (int kk = 0; kk < BK; kk += 32) {
#pragma unroll
            // qg = kk/8 + q : global 16-B chunk index within the row
            for (int dummy = 0; dummy < 1; dummy++) {}
            bf16x8 av[MT], bv[NT];
#pragma unroll
            for (int mi = 0; mi < MT; mi++) {
                int arow = wrow * WM + mi * 16 + r;
                av[mi] = *(const bf16x8*)&lds_a[arow * BK + ((kk / 8 + q) ^ (arow & 7)) * 8];
            }
#pragma unroll
            for (int ni = 0; ni < NT; ni++) {
                int brow = wcol * WN + ni * 16 + r;
                bv[ni] = *(const bf16x8*)&lds_b[brow * BK + ((kk / 8 + q) ^ (brow & 7)) * 8];
            }
#pragma unroll
            for (int mi = 0; mi < MT; mi++)
#pragma unroll
                for (int ni = 0; ni < NT; ni++)
                    acc[mi][ni] = __builtin_amdgcn_mfma_f32_16x16x32_bf16(av[mi], bv[ni], acc[mi][ni], 0, 0, 0);
        }
        __syncthreads();
    }

    // epilogue: C/D layout col = lane&15, row = q*4 + d
#pragma unroll
    for (int mi = 0; mi < MT; mi++) {
        int row = bm + wrow * WM + mi * 16 + q * 4;
#pragma unroll
        for (int ni = 0; ni < NT; ni++) {
            int cc = bn + wcol * WN + ni * 16 + r;
#pragma unroll
            for (int d = 0; d < 4; d++) {
                if constexpr (OUT == 0) {
                    ((unsigned short*)Cptr)[(size_t)(row + d) * Nc + cc] = f2bf(acc[mi][ni][d]);
                } else {
                    ((unsigned char*)Cptr)[(size_t)(row + d) * Nc + cc] = f2fp8(acc[mi][ni][d]);
                }
            }
        }
    }
}

// ---------- SPMM (F=256, fp8 Z): wave per row, scalarized edge stream ----------
// R5-proven config: UN=16 main / UN=8 masked tail (R6's UN=32 regressed 33%).
__global__ __launch_bounds__(256) void spmm_f256_fp8(const int* __restrict__ rp, const int2* __restrict__ cpack,
                                                     const unsigned char* __restrict__ Z8,
                                                     const float* __restrict__ bias, unsigned short* __restrict__ H, int N) {
    int w = __builtin_amdgcn_readfirstlane((int)((blockIdx.x * 256 + threadIdx.x) >> 6));
    if (w >= N) return;
    int lane = threadIdx.x & 63;
    int f4 = lane * 4;                       // byte offset into 256-B fp8 row
    int s = __builtin_amdgcn_readfirstlane(rp[w]);
    int e = __builtin_amdgcn_readfirstlane(rp[w + 1]);
    f32x2 acc01 = {0.f, 0.f}, acc23 = {0.f, 0.f};
    int j = s;

#define EDGE_BLK(UN, MASKED) { \
        int2 eb[UN]; \
        _Pragma("unroll") \
        for (int t = 0; t < UN; t++) eb[t] = cpack[j + t]; \
        _Pragma("unroll") \
        for (int t = 0; t < UN; t++) { \
            int ex = __builtin_amdgcn_readfirstlane(eb[t].x); \
            int ew = __builtin_amdgcn_readfirstlane(eb[t].y); \
            if (MASKED) ew = (j + t < e) ? ew : 0; \
            float wt = __int_as_float(ew); \
            unsigned z = *(const unsigned*)(Z8 + (size_t)(unsigned)ex + f4); \
            f32x2 lo = __builtin_amdgcn_cvt_pk_f32_fp8((int)z, false); \
            f32x2 hi = __builtin_amdgcn_cvt_pk_f32_fp8((int)z, true);  \
            f32x2 wv = {wt, wt}; \
            acc01 += wv * lo; \
            acc23 += wv * hi; \
        } }

    for (; j + 16 <= e; j += 16) EDGE_BLK(16, false)
    for (; j < e; j += 8)        EDGE_BLK(8,  true)   // masked tail; cpack padded by 16 zeros
#undef EDGE_BLK

    float4 b = *(const float4*)(bias + f4);
    float a0 = fmaxf(acc01.x + b.x, 0.f), a1 = fmaxf(acc01.y + b.y, 0.f);
    float a2 = fmaxf(acc23.x + b.z, 0.f), a3 = fmaxf(acc23.y + b.w, 0.f);
    ushort4 o; o.x = f2bf(a0); o.y = f2bf(a1); o.z = f2bf(a2); o.w = f2bf(a3);
    *(ushort4*)(H + (size_t)w * 256 + f4) = o;
}

// ---------- SPMM (F=64, bf16 Z) + bias + log_softmax ----------
__global__ __launch_bounds__(256) void spmm_f64_lsm(const int* __restrict__ rp, const int2* __restrict__ cpack,
                                                    const unsigned short* __restrict__ Z,
                                                    const float* __restrict__ bias, float* __restrict__ out, int N) {
    int w = __builtin_amdgcn_readfirstlane((int)((blockIdx.x * 256 + threadIdx.x) >> 6));
    if (w >= N) return;
    int lane = threadIdx.x & 63;
    const unsigned char* Zb = (const unsigned char*)Z;
    int s = __builtin_amdgcn_readfirstlane(rp[w]);
    int e = __builtin_amdgcn_readfirstlane(rp[w + 1]);
    float acc = 0.f;
    int j = s;

#define EDGE_BLK(UN, MASKED) { \
        int2 eb[UN]; \
        _Pragma("unroll") \
        for (int t = 0; t < UN; t++) eb[t] = cpack[j + t]; \
        _Pragma("unroll") \
        for (int t = 0; t < UN; t++) { \
            int ex = __builtin_amdgcn_readfirstlane(eb[t].x); \
            int ew = __builtin_amdgcn_readfirstlane(eb[t].y); \
            if (MASKED) ew = (j + t < e) ? ew : 0; \
            float wt = __int_as_float(ew); \
            /* ex = col*256 ; bf16 row stride = 128 B -> ex>>1 */ \
            unsigned short z = *(const unsigned short*)(Zb + (size_t)(unsigned)(ex >> 1) + lane * 2); \
            acc += wt * bf2f(z); \
        } }

    for (; j + 8 <= e; j += 8) EDGE_BLK(8, false)
    for (; j < e; j += 4)      EDGE_BLK(4, true)   // masked tail; cpack padded by 16 zeros
#undef EDGE_BLK

    float a = acc + bias[lane];
    float m = a;
#pragma unroll
    for (int off = 32; off >= 1; off >>= 1) m = fmaxf(m, __shfl_xor(m, off, 64));
    float p = __expf(a - m);
    float sum = p;
#pragma unroll
    for (int off = 32; off >= 1; off >>= 1) sum += __shfl_xor(sum, off, 64);
    out[(size_t)w * 64 + lane] = a - m - __logf(sum);
}

// ---------- launch ----------
extern "C" void kernel_launch(void* const* d_in, const int* in_sizes, int n_in,
                              void* d_out, int out_size, void* d_ws, size_t ws_size,
                              hipStream_t stream) {
    const float* x  = (const float*)d_in[0];
    const int*   er = (const int*)  d_in[1];
    const int*   ec = (const int*)  d_in[2];
    const float* ev = (const float*)d_in[3];
    const float* W1 = (const float*)d_in[4];
    const float* b1 = (const float*)d_in[5];
    const float* W2 = (const float*)d_in[6];
    const float* b2 = (const float*)d_in[7];
    const float* W3 = (const float*)d_in[8];
    const float* b3 = (const float*)d_in[9];

    const int N = N_NODES, E = N_EDGES;

    char* p = (char*)d_ws;
    auto alloc = [&](size_t bytes) -> char* {
        char* q = p; p += (bytes + 255) & ~(size_t)255; return q;
    };
    unsigned short* Wt1    = (unsigned short*)alloc((size_t)256 * 512 * 2);
    unsigned short* Wt2    = (unsigned short*)alloc((size_t)256 * 256 * 2);
    unsigned short* Wt3    = (unsigned short*)alloc((size_t)64  * 256 * 2);
    int*            rp     = (int*)  alloc((size_t)(N + 1) * 4);
    int*            blkCnt = (int*)  alloc((size_t)NBLK * NB * 4);
    int*            blkOff = (int*)  alloc((size_t)NBLK * NB * 4);
    int*            bktTot = (int*)  alloc((size_t)NB * 4);
    int*            bktSt  = (int*)  alloc((size_t)(NB + 1) * 4);
    int2*           cpack  = (int2*) alloc((size_t)(E + 16) * 8);   // +16 zero pad for masked tails
    unsigned char*  Z8     = (unsigned char*) alloc((size_t)MPAD * 256);      // fp8 Z (layers 1-2)
    unsigned short* bufA   = (unsigned short*)alloc((size_t)MPAD * 256 * 2);  // bf16 Z (layer 3) / cpackT overlay
    unsigned short* bufB   = (unsigned short*)alloc((size_t)MPAD * 256 * 2);  // bf16 H
    int2*           cpackT = (int2*)bufA;   // overlay: bufA unused until gemm3

    // CSR build
    bucket_hist   <<<NBLK, 256, 0, stream>>>(er, blkCnt);
    bucket_scan_a <<<NB,   256, 0, stream>>>(blkCnt, blkOff, bktTot);
    bucket_scan_b <<<1,   1024, 0, stream>>>(bktTot, bktSt, rp, E, cpack + E);
    bucket_scatter<<<NBLK, 1024, 0, stream>>>(er, ec, ev, blkCnt, blkOff, bktSt, cpackT);
    bucket_sort   <<<NB,   256, 0, stream>>>(cpackT, bktSt, cpack, rp);

    // weights -> bf16 transposed (one launch)
    transpose_all<<<(512*256 + 256*256 + 256*64 + 255) / 256, 256, 0, stream>>>(W1, Wt1, W2, Wt2, W3, Wt3);

    // layer 1: Z8 = fp8(x @ W1) ; H = relu(spmm(Z8) + b1)
    // 8 waves (4x2), per-wave 32x64 -> acc 32 AGPR; gload_lds staging
    gemm_mfma<128, 128, 64, 4, 2, true , 1><<<dim3(MPAD / 128, 2), 512, 0, stream>>>(x,    Wt1, Z8,   512, 256, N - 1);
    spmm_f256_fp8<<<N / 4, 256, 0, stream>>>(rp, cpack, Z8, b1, bufB, N);
    // layer 2
    gemm_mfma<128, 128, 64, 4, 2, false, 1><<<dim3(MPAD / 128, 2), 512, 0, stream>>>(bufB, Wt2, Z8,   256, 256, N - 1);
    spmm_f256_fp8<<<N / 4, 256, 0, stream>>>(rp, cpack, Z8, b2, bufB, N);
    // layer 3 (bf16 Z to protect logits) + fused bias + log_softmax
    gemm_mfma<128, 64, 64, 4, 2, false, 0><<<dim3(MPAD / 128, 1), 512, 0, stream>>>(bufB, Wt3, bufA, 256, 64, N - 1);
    spmm_f64_lsm<<<N / 4, 256, 0, stream>>>(rp, cpack, bufA, b3, (float*)d_out, N);
}